// Round 4
// baseline (124.626 us; speedup 1.0000x reference)
//
#include <hip/hip_runtime.h>
#include <hip/hip_bf16.h>

// Conv2dKan via implicit-GEMM MFMA. b=16, cin=cout=64, H=W=32, K=3, PAD=1, BASIS=8.
// out[b,o,pix] = bias[o] + sum_{i,k,s8} Wt[i,k,o,s]*Ah[b,i,pix+off(k),s]
//   Wt[...,0]=w, Wt[...,s]=w*c[s] (s=1..7), bf16
//   Ah = [silu(x), T1..T7(tanh x)] on 34x34 halo grid; border = act(0) = [0,0,-1,0,1,0,-1,0]
//   bias[o] = sum_{i,k} w*c[...,0]  (T0==1)
// MFMA 16x16x32 bf16: A=weights (M=o), B=activations (N=pix).
// R4: register-block c=2 pixel-groups per wave (halves wf LDS reads per MFMA),
//     split N into 2 halves of 32 o (halves staging + LDS footprint -> 36864B),
//     grid 512 blocks x 2 waves -> 2 blocks/CU (barrier drain overlaps across blocks).

#define CIN   64
#define COUT  64
#define HW    32
#define LL    1024
#define NS    8
#define AH    34
#define AHC   1156

typedef __attribute__((ext_vector_type(8))) short short8;
typedef __attribute__((ext_vector_type(4))) float f32x4;

// ws layout (bytes):
//   [0)       Wt   : 64*9*64*8 bf16 = 589824 B   ([i][k][o][s])
//   [589824)  bias : 64 f32         = 256 B
//   [590080)  Ah   : 16*64*1156*8 bf16 = 18939904 B

__global__ void prep_kernel(const float* __restrict__ w,
                            const float* __restrict__ c,
                            __hip_bfloat16* __restrict__ Wt,
                            float* __restrict__ bias) {
    if (blockIdx.x == 144) {
        // bias[o] = sum_{i,k} w[i,o,k]*c[i,o,k,0]
        __shared__ float red[256];
        const int o = threadIdx.x & 63;
        const int part = threadIdx.x >> 6;   // 4 parts x 16 i
        float v = 0.f;
        for (int ii = 0; ii < 16; ++ii) {
            const int i = part * 16 + ii;
#pragma unroll
            for (int k = 0; k < 9; ++k) {
                const int idx = (i * COUT + o) * 9 + k;
                v += w[idx] * c[idx * 8];
            }
        }
        red[threadIdx.x] = v;
        __syncthreads();
        if (part == 0) bias[o] = red[o] + red[64 + o] + red[128 + o] + red[192 + o];
        return;
    }
    const int tid = blockIdx.x * 256 + threadIdx.x;   // < 36864 = 64i*9k*64o
    const int i = tid / (9 * COUT);
    const int r = tid - i * 9 * COUT;
    const int k = r / COUT;
    const int o = r - k * COUT;
    const int widx = (i * COUT + o) * 9 + k;
    const float wv = w[widx];
    __hip_bfloat16* dst = Wt + (size_t)tid * NS;      // tid == (i*9+k)*64+o
    dst[0] = __float2bfloat16(wv);
#pragma unroll
    for (int s = 1; s < 8; ++s) dst[s] = __float2bfloat16(wv * c[widx * 8 + s]);
}

__global__ void act_kernel(const float* __restrict__ x,
                           __hip_bfloat16* __restrict__ Ah) {
    int idx = blockIdx.x * 256 + threadIdx.x;   // 1,183,744 = 16*64*1156
    int bi = idx / AHC;
    int r  = idx - bi * AHC;
    int yy = r / AH;
    int xx = r - yy * AH;
    __align__(16) __hip_bfloat16 hv[8];
    if (yy >= 1 && yy <= 32 && xx >= 1 && xx <= 32) {
        float xv = x[bi * LL + (yy - 1) * HW + (xx - 1)];
        float e  = __expf(-xv);
        float res = xv / (1.f + e);              // silu
        float e2 = __expf(2.f * xv);
        float t  = 1.f - 2.f / (e2 + 1.f);       // tanh
        float T2 = 2.f * t * t  - 1.f;
        float T3 = 2.f * t * T2 - t;
        float T4 = 2.f * t * T3 - T2;
        float T5 = 2.f * t * T4 - T3;
        float T6 = 2.f * t * T5 - T4;
        float T7 = 2.f * t * T6 - T5;
        hv[0] = __float2bfloat16(res); hv[1] = __float2bfloat16(t);
        hv[2] = __float2bfloat16(T2);  hv[3] = __float2bfloat16(T3);
        hv[4] = __float2bfloat16(T4);  hv[5] = __float2bfloat16(T5);
        hv[6] = __float2bfloat16(T6);  hv[7] = __float2bfloat16(T7);
    } else {
        // activation of x=0: [0, 0, -1, 0, 1, 0, -1, 0]
        ((unsigned int*)hv)[0] = 0x00000000u;
        ((unsigned int*)hv)[1] = 0x0000BF80u;
        ((unsigned int*)hv)[2] = 0x00003F80u;
        ((unsigned int*)hv)[3] = 0x0000BF80u;
    }
    *(float4*)(Ah + (size_t)idx * NS) = *(const float4*)hv;
}

// grid (16 row-pairs, 16 batches, 2 o-halves), block 128 (2 waves).
// Wave: 1 pixel row (32 pix = 2 B-frag groups) x 32 o (2 A-frags). Full K, no atomics.
__global__ __launch_bounds__(128) void kan_mfma_kernel(
        const __hip_bfloat16* __restrict__ Wt,
        const float* __restrict__ bias,
        const __hip_bfloat16* __restrict__ Ah,
        float* __restrict__ out) {
    // weight chunk: 8i * 9k * 32o * 8s bf16 = 36864 B
    __shared__ __align__(16) unsigned short Wlds[18432];

    const int tid  = threadIdx.x;
    const int wv   = tid >> 6;        // wave 0..1 -> row within pair
    const int lane = tid & 63;
    const int quad = lane >> 4;       // channel offset within MFMA K (4 ch)
    const int l16  = lane & 15;

    const int y0 = blockIdx.x * 2;
    const int b  = blockIdx.y;
    const int oh = blockIdx.z;        // o-half: o in [oh*32, oh*32+32)

    const int py = y0 + wv;
    const unsigned short* ap0 = (const unsigned short*)Ah +
        (((size_t)(b * CIN + quad)) * AHC + (py + 1) * AH + (1 + l16)) * NS;

    f32x4 acc[2][2];   // [nt][cg]
#pragma unroll
    for (int nt = 0; nt < 2; ++nt)
#pragma unroll
        for (int cg = 0; cg < 2; ++cg) acc[nt][cg] = (f32x4){0.f, 0.f, 0.f, 0.f};

    const float4* wsrc = (const float4*)Wt;   // float4 idx = (i*9+k)*64 + o
    for (int ig = 0; ig < 8; ++ig) {
        __syncthreads();
        // stage 2304 float4: dst j = (ilocal*9+k)*32+oo ; src = (ig*72 + (j>>5))*64 + oh*32 + (j&31)
#pragma unroll
        for (int p = 0; p < 18; ++p) {
            const int j = p * 128 + tid;
            ((float4*)Wlds)[j] = wsrc[(size_t)(ig * 72 + (j >> 5)) * 64 + (oh << 5) + (j & 31)];
        }
        __syncthreads();

#pragma unroll
        for (int istep = 0; istep < 2; ++istep) {
            const unsigned short* ap = ap0 + (size_t)(ig * 8 + istep * 4) * AHC * NS;
            const unsigned short* wb = Wlds + (istep * 4 + quad) * 9 * 32 * NS;
#pragma unroll
            for (int k = 0; k < 9; ++k) {
                const int dy = k / 3 - 1, dx = k % 3 - 1;
                short8 af0 = *(const short8*)(ap + (dy * AH + dx) * NS);
                short8 af1 = *(const short8*)(ap + (dy * AH + dx + 16) * NS);
#pragma unroll
                for (int nt = 0; nt < 2; ++nt) {
                    short8 wf = *(const short8*)(wb + (k * 32 + nt * 16 + l16) * NS);
                    acc[nt][0] = __builtin_amdgcn_mfma_f32_16x16x32_bf16(wf, af0, acc[nt][0], 0, 0, 0);
                    acc[nt][1] = __builtin_amdgcn_mfma_f32_16x16x32_bf16(wf, af1, acc[nt][1], 0, 0, 0);
                }
            }
        }
    }

    // D: row = o_local = quad*4+r, col = pixel = cg*16 + l16
    const int pixbase = py * HW + l16;
#pragma unroll
    for (int nt = 0; nt < 2; ++nt) {
#pragma unroll
        for (int cg = 0; cg < 2; ++cg) {
#pragma unroll
            for (int r = 0; r < 4; ++r) {
                const int o = (oh << 5) + nt * 16 + quad * 4 + r;
                out[((size_t)(b * COUT + o)) * LL + pixbase + cg * 16] = acc[nt][cg][r] + bias[o];
            }
        }
    }
}

extern "C" void kernel_launch(void* const* d_in, const int* in_sizes, int n_in,
                              void* d_out, int out_size, void* d_ws, size_t ws_size,
                              hipStream_t stream) {
    const float* x = (const float*)d_in[0];
    const float* w = (const float*)d_in[1];
    const float* c = (const float*)d_in[2];
    float* out = (float*)d_out;

    char* ws = (char*)d_ws;
    __hip_bfloat16* Wt   = (__hip_bfloat16*)(ws);
    float*          bias = (float*)(ws + 589824);
    __hip_bfloat16* Ah   = (__hip_bfloat16*)(ws + 590080);

    prep_kernel<<<145, 256, 0, stream>>>(w, c, Wt, bias);
    act_kernel<<<4624, 256, 0, stream>>>(x, Ah);
    kan_mfma_kernel<<<dim3(16, 16, 2), 128, 0, stream>>>(Wt, bias, Ah, out);
}

// Round 5
// 112.828 us; speedup vs baseline: 1.1046x; 1.1046x over previous
//
#include <hip/hip_runtime.h>
#include <hip/hip_bf16.h>

// Conv2dKan via implicit-GEMM MFMA (32x32x16 bf16). b=16, cin=cout=64, H=W=32, K=3, PAD=1, BASIS=8.
// out[b,o,pix] = bias[o] + sum_{i,k,s8} Wt[i,k,o,s]*Ah[b,i,pix+off(k),s]
//   Wt[...,0]=w, Wt[...,s]=w*c[s] (s=1..7), bf16   layout [i][kpos][o][s]
//   Ah = [silu(x), T1..T7(tanh x)] on 34x34 halo grid; border = act(0) = [0,0,-1,0,1,0,-1,0]
//   bias[o] = sum_{i,k} w*c[...,0]  (T0==1)
// MFMA 32x32x16: A=weights (M=32 o), B=activations (N=32 pix), K=16 = 2 channels x 8 s.
//   A/B frag: elem j=0..7, k=(lane>>5)*8+j (lane-half picks channel of the pair), m/n=lane&31.
//   C/D: col(pix)=lane&31, row(o)=(reg&3)+8*(reg>>2)+4*(lane>>5)   [m74/m101]
// R5: 32x32 halves LDS+global bytes per FLOP vs R3; 2 interleaved accs hide MFMA latency;
//     prep fused into act launch. Block=4 waves (o-half x row), 256 blocks, full K, no atomics.

#define CIN   64
#define COUT  64
#define HW    32
#define LL    1024
#define NS    8
#define AH    34
#define AHC   1156

typedef __attribute__((ext_vector_type(8))) short short8;
typedef __attribute__((ext_vector_type(16))) float f32x16;

// ws layout (bytes):
//   [0)       Wt   : 64*9*64*8 bf16 = 589824 B   ([i][kpos][o][s])
//   [589824)  bias : 64 f32         = 256 B
//   [590080)  Ah   : 16*64*1156*8 bf16 = 18939904 B

__global__ void prep_act_kernel(const float* __restrict__ x,
                                const float* __restrict__ w,
                                const float* __restrict__ c,
                                __hip_bfloat16* __restrict__ Wt,
                                float* __restrict__ bias,
                                __hip_bfloat16* __restrict__ Ah) {
    int bx = blockIdx.x;
    if (bx >= 4624) {
        bx -= 4624;                      // prep part: 145 blocks
        if (bx == 144) {
            // bias[o] = sum_{i,k} w[i,o,k]*c[i,o,k,0]
            __shared__ float red[256];
            const int o = threadIdx.x & 63;
            const int part = threadIdx.x >> 6;
            float v = 0.f;
            for (int ii = 0; ii < 16; ++ii) {
                const int i = part * 16 + ii;
#pragma unroll
                for (int k = 0; k < 9; ++k) {
                    const int idx = (i * COUT + o) * 9 + k;
                    v += w[idx] * c[idx * 8];
                }
            }
            red[threadIdx.x] = v;
            __syncthreads();
            if (part == 0) bias[o] = red[o] + red[64 + o] + red[128 + o] + red[192 + o];
            return;
        }
        const int tid = bx * 256 + threadIdx.x;   // < 36864 = 64i*9k*64o
        const int i = tid / (9 * COUT);
        const int r = tid - i * 9 * COUT;
        const int k = r / COUT;
        const int o = r - k * COUT;
        const int widx = (i * COUT + o) * 9 + k;
        const float wv = w[widx];
        __hip_bfloat16* dst = Wt + (size_t)tid * NS;   // tid == (i*9+k)*64+o
        dst[0] = __float2bfloat16(wv);
#pragma unroll
        for (int s = 1; s < 8; ++s) dst[s] = __float2bfloat16(wv * c[widx * 8 + s]);
        return;
    }

    // act part: 4624 blocks, 1,183,744 threads = 16*64*1156 halo cells
    const int idx = bx * 256 + threadIdx.x;
    const int bi = idx / AHC;
    const int r  = idx - bi * AHC;
    const int yy = r / AH;
    const int xx = r - yy * AH;
    __align__(16) __hip_bfloat16 hv[8];
    if (yy >= 1 && yy <= 32 && xx >= 1 && xx <= 32) {
        float xv = x[bi * LL + (yy - 1) * HW + (xx - 1)];
        float e  = __expf(-xv);
        float res = xv / (1.f + e);              // silu
        float e2 = __expf(2.f * xv);
        float t  = 1.f - 2.f / (e2 + 1.f);       // tanh
        float T2 = 2.f * t * t  - 1.f;
        float T3 = 2.f * t * T2 - t;
        float T4 = 2.f * t * T3 - T2;
        float T5 = 2.f * t * T4 - T3;
        float T6 = 2.f * t * T5 - T4;
        float T7 = 2.f * t * T6 - T5;
        hv[0] = __float2bfloat16(res); hv[1] = __float2bfloat16(t);
        hv[2] = __float2bfloat16(T2);  hv[3] = __float2bfloat16(T3);
        hv[4] = __float2bfloat16(T4);  hv[5] = __float2bfloat16(T5);
        hv[6] = __float2bfloat16(T6);  hv[7] = __float2bfloat16(T7);
    } else {
        // activation of x=0: [0, 0, -1, 0, 1, 0, -1, 0]
        ((unsigned int*)hv)[0] = 0x00000000u;
        ((unsigned int*)hv)[1] = 0x0000BF80u;
        ((unsigned int*)hv)[2] = 0x00003F80u;
        ((unsigned int*)hv)[3] = 0x0000BF80u;
    }
    *(float4*)(Ah + (size_t)idx * NS) = *(const float4*)hv;
}

// grid (16 row-pairs, 16 batches), block 256 = 4 waves: wave = (o-half, row-in-pair).
// Wave tile: 32 o x 32 pix (one image row), full K=4608 = 8 ig x 4 ipair x 9 kpos steps.
__global__ __launch_bounds__(256) void kan_mfma_kernel(
        const __hip_bfloat16* __restrict__ Wt,
        const float* __restrict__ bias,
        const __hip_bfloat16* __restrict__ Ah,
        float* __restrict__ out) {
    __shared__ __align__(16) unsigned short Wlds[36864];   // 8ch x 9k x 64o x 8s = 73728 B

    const int tid  = threadIdx.x;
    const int wv   = tid >> 6;
    const int lane = tid & 63;
    const int l32  = lane & 31;
    const int lh   = lane >> 5;       // k-subgroup: channel-of-pair; D-row +4*lh

    const int row = blockIdx.x * 2 + (wv & 1);   // image row 0..31
    const int b   = blockIdx.y;
    const int o0  = (wv >> 1) * 32;

    const unsigned short* AhU = (const unsigned short*)Ah;
    // lane af base (ushorts): ((b*64 + lh)*1156 + (row+1)*34 + 1 + l32)*8 ; +ig,ipair channel strides
    const size_t abase = ((size_t)(b * CIN + lh) * AHC + (row + 1) * AH + 1 + l32) * NS;

    f32x16 acc0, acc1;
#pragma unroll
    for (int r = 0; r < 16; ++r) { acc0[r] = 0.f; acc1[r] = 0.f; }

    const float4* wsrc = (const float4*)Wt;
    for (int ig = 0; ig < 8; ++ig) {
        __syncthreads();
#pragma unroll
        for (int p = 0; p < 18; ++p)
            ((float4*)Wlds)[p * 256 + tid] = wsrc[(size_t)ig * 4608 + p * 256 + tid];
        __syncthreads();

        const unsigned short* ap_ig = AhU + abase + (size_t)ig * 8 * AHC * NS;
#pragma unroll
        for (int ipair = 0; ipair < 4; ++ipair) {
            const unsigned short* ap = ap_ig + (size_t)ipair * 2 * AHC * NS;
            const unsigned short* wb = Wlds + (size_t)((ipair * 2 + lh) * 9) * COUT * NS
                                            + (o0 + l32) * NS;
#pragma unroll
            for (int kpos = 0; kpos < 9; ++kpos) {
                const int dy = kpos / 3 - 1, dx = kpos % 3 - 1;
                short8 af = *(const short8*)(ap + (dy * AH + dx) * NS);
                short8 wf = *(const short8*)(wb + kpos * COUT * NS);
                if (kpos & 1)
                    acc1 = __builtin_amdgcn_mfma_f32_32x32x16_bf16(wf, af, acc1, 0, 0, 0);
                else
                    acc0 = __builtin_amdgcn_mfma_f32_32x32x16_bf16(wf, af, acc0, 0, 0, 0);
            }
        }
    }

    // D: col(pix)=l32, row(o_local)=(r&3)+8*(r>>2)+4*lh
    const int pixb = row * HW + l32;
#pragma unroll
    for (int r = 0; r < 16; ++r) {
        const int o = o0 + (r & 3) + 8 * (r >> 2) + 4 * lh;
        out[(size_t)(b * COUT + o) * LL + pixb] = acc0[r] + acc1[r] + bias[o];
    }
}

extern "C" void kernel_launch(void* const* d_in, const int* in_sizes, int n_in,
                              void* d_out, int out_size, void* d_ws, size_t ws_size,
                              hipStream_t stream) {
    const float* x = (const float*)d_in[0];
    const float* w = (const float*)d_in[1];
    const float* c = (const float*)d_in[2];
    float* out = (float*)d_out;

    char* ws = (char*)d_ws;
    __hip_bfloat16* Wt   = (__hip_bfloat16*)(ws);
    float*          bias = (float*)(ws + 589824);
    __hip_bfloat16* Ah   = (__hip_bfloat16*)(ws + 590080);

    prep_act_kernel<<<4769, 256, 0, stream>>>(x, w, c, Wt, bias, Ah);
    kan_mfma_kernel<<<dim3(16, 16), 256, 0, stream>>>(Wt, bias, Ah, out);
}